// Round 1
// 483.666 us; speedup vs baseline: 1.0020x; 1.0020x over previous
//
#include <hip/hip_runtime.h>
#include <hip/hip_bf16.h>

// Problem constants
#define T_TOK 128
#define N_EXP 8
#define HID   1024
#define INTER 4096

typedef __bf16 bf16x8 __attribute__((ext_vector_type(8)));
typedef __bf16 bf16x4 __attribute__((ext_vector_type(4)));
typedef float  f32x4  __attribute__((ext_vector_type(4)));

// ---------------------------------------------------------------------------
// Kernel 1: routing. softmax over 8 logits -> top2 -> renormalized scales.
// ---------------------------------------------------------------------------
__global__ void route_kernel(const float* __restrict__ routing,
                             int* __restrict__ cnt,
                             int* __restrict__ tok,
                             float* __restrict__ scal) {
    int t = threadIdx.x;            // token id 0..127
    int wave = t >> 6, lane = t & 63;

    float l[N_EXP];
#pragma unroll
    for (int e = 0; e < N_EXP; ++e) l[e] = routing[t * N_EXP + e];

    int i1 = 0; float v1 = l[0];
#pragma unroll
    for (int e = 1; e < N_EXP; ++e) if (l[e] > v1) { v1 = l[e]; i1 = e; }
    int i2 = -1; float v2 = -1e30f;
#pragma unroll
    for (int e = 0; e < N_EXP; ++e) if (e != i1 && l[e] > v2) { v2 = l[e]; i2 = e; }

    float s1 = 1.0f / (1.0f + __expf(v2 - v1));
    float s2 = 1.0f - s1;

    __shared__ unsigned long long wmask[2][N_EXP];
#pragma unroll
    for (int e = 0; e < N_EXP; ++e) {
        bool sel = (i1 == e) || (i2 == e);
        unsigned long long m = __ballot(sel);
        if (lane == 0) wmask[wave][e] = m;
    }
    __syncthreads();
#pragma unroll
    for (int e = 0; e < N_EXP; ++e) {
        bool sel = (i1 == e) || (i2 == e);
        unsigned long long m = __ballot(sel);
        int pre  = __popcll(m & ((1ull << lane) - 1ull));
        int base = (wave == 1) ? __popcll(wmask[0][e]) : 0;
        if (sel) {
            int slot = base + pre;
            tok [e * T_TOK + slot] = t;
            scal[e * T_TOK + slot] = (i1 == e) ? s1 : s2;
        }
        if (t == 0) cnt[e] = __popcll(wmask[0][e]) + __popcll(wmask[1][e]);
    }
}

// ---------------------------------------------------------------------------
// Kernel 2: gather routed hidden rows into compact bf16 A-buffer.
// ---------------------------------------------------------------------------
__global__ void prep_kernel(const float* __restrict__ hidden,
                            const int* __restrict__ cnt,
                            const int* __restrict__ tok,
                            __bf16* __restrict__ abuf) {
    int b = blockIdx.x;
    int e = b >> 7, s = b & 127;
    if (s >= cnt[e]) return;
    int t = tok[e * T_TOK + s];
    const float4* src = (const float4*)(hidden + (size_t)t * HID);
    __bf16* dst = abuf + ((size_t)e * T_TOK + s) * HID;
#pragma unroll
    for (int it = 0; it < 4; ++it) {
        int idx = it * 64 + threadIdx.x;
        float4 v = src[idx];
        bf16x4 pk;
        pk[0] = (__bf16)v.x; pk[1] = (__bf16)v.y;
        pk[2] = (__bf16)v.z; pk[3] = (__bf16)v.w;
        *(bf16x4*)(dst + idx * 4) = pk;
    }
}

// ---------------------------------------------------------------------------
// LDS-staged GEMMs.
//
// Weight rows are streamed as wave-contiguous 1KB bursts (64 lanes x float4
// along one row), cvt'd to bf16 in-register, and ds_write'd into a swizzled
// LDS tile. XOR swizzle: byte ^= (row&7)<<4 — identical on write and read,
// bijective within each row, spreads the stride-512B fragment reads across
// all banks (unswizzled: 16-way conflict on ds_read_b128).
// ---------------------------------------------------------------------------
#define BK1 256                 // f32 elements staged per K-step
#define LDS_ROWB (BK1 * 2)      // 512 bytes per LDS row (bf16)

// ---------------------------------------------------------------------------
// Kernel 3: GEMM1 + swiglu. 64 lin cols + 64 gate cols per block, staged.
// ---------------------------------------------------------------------------
template<int MG>
__device__ __forceinline__ void g1_body(const float* __restrict__ pl,
                                        const float* __restrict__ pg,
                                        const __bf16* __restrict__ ap,
                                        char* __restrict__ ldsb,
                                        int wave, int lane,
                                        f32x4* __restrict__ accl,
                                        f32x4* __restrict__ accg) {
    const int lr = lane & 15, lq = lane >> 4;
    const int sread = (lr & 7) << 4;          // (row&7)<<4; wave*16 ≡ 0 mod 8
    const char* blp = ldsb + (size_t)(wave * 16 + lr) * LDS_ROWB;
    const char* bgp = blp + (size_t)64 * LDS_ROWB;

    for (int ks = 0; ks < HID; ks += BK1) {
        // ---- stage: 128 rows (64 lin + 64 gate) x 256 f32 -> bf16 LDS ----
#pragma unroll 8
        for (int it = 0; it < 16; ++it) {
            int row = it * 4 + wave;          // 0..63
            float4 v = *(const float4*)(pl + (size_t)row * HID + ks);
            bf16x4 pk;
            pk[0] = (__bf16)v.x; pk[1] = (__bf16)v.y;
            pk[2] = (__bf16)v.z; pk[3] = (__bf16)v.w;
            *(bf16x4*)(ldsb + (size_t)row * LDS_ROWB +
                       ((lane * 8) ^ ((row & 7) << 4))) = pk;
        }
#pragma unroll 8
        for (int it = 0; it < 16; ++it) {
            int row = it * 4 + wave;
            float4 v = *(const float4*)(pg + (size_t)row * HID + ks);
            bf16x4 pk;
            pk[0] = (__bf16)v.x; pk[1] = (__bf16)v.y;
            pk[2] = (__bf16)v.z; pk[3] = (__bf16)v.w;
            *(bf16x4*)(ldsb + (size_t)(64 + row) * LDS_ROWB +
                       ((lane * 8) ^ ((row & 7) << 4))) = pk;
        }
        __syncthreads();
        // ---- compute: fragments from LDS (B) + L2-hot global (A) ----
#pragma unroll
        for (int kk = 0; kk < BK1; kk += 32) {
            int off = (kk * 2 + lq * 16) ^ sread;
            bf16x8 BL = *(const bf16x8*)(blp + off);
            bf16x8 BG = *(const bf16x8*)(bgp + off);
            bf16x8 A[MG];
#pragma unroll
            for (int m = 0; m < MG; ++m)
                A[m] = *(const bf16x8*)(ap + (size_t)m * 16 * HID + ks + kk);
#pragma unroll
            for (int m = 0; m < MG; ++m) {
                accl[m] = __builtin_amdgcn_mfma_f32_16x16x32_bf16(A[m], BL, accl[m], 0, 0, 0);
                accg[m] = __builtin_amdgcn_mfma_f32_16x16x32_bf16(A[m], BG, accg[m], 0, 0, 0);
            }
        }
        __syncthreads();
    }
}

__global__ __launch_bounds__(256) void gemm1_kernel(
    const float* __restrict__ w1,
    const int* __restrict__ cnt,
    const __bf16* __restrict__ abuf,
    __bf16* __restrict__ act) {
    __shared__ __align__(16) __bf16 lds[128 * BK1];   // 64 KB
    int bx = blockIdx.x;                 // 0..511
    int e  = bx >> 6, nb = bx & 63;
    int wave = threadIdx.x >> 6, lane = threadIdx.x & 63;
    int c  = cnt[e];
    if (c == 0) return;
    int mgs = (c + 15) >> 4;
    int lr = lane & 15;
    int lq = lane >> 4;
    int n0b = nb * 64;

    const float* w1e = w1 + (size_t)e * 2 * INTER * HID;
    const float* pl  = w1e + (size_t)n0b * HID + lane * 4;
    const float* pg  = w1e + ((size_t)INTER + n0b) * HID + lane * 4;
    const __bf16* ap = abuf + ((size_t)e * T_TOK + lr) * HID + lq * 8;

    f32x4 accl[8], accg[8];
#pragma unroll
    for (int m = 0; m < 8; ++m) {
        accl[m] = (f32x4){0.f, 0.f, 0.f, 0.f};
        accg[m] = (f32x4){0.f, 0.f, 0.f, 0.f};
    }

    char* ldsb = (char*)lds;
    switch (mgs) {
        case 1: g1_body<1>(pl, pg, ap, ldsb, wave, lane, accl, accg); break;
        case 2: g1_body<2>(pl, pg, ap, ldsb, wave, lane, accl, accg); break;
        case 3: g1_body<3>(pl, pg, ap, ldsb, wave, lane, accl, accg); break;
        case 4: g1_body<4>(pl, pg, ap, ldsb, wave, lane, accl, accg); break;
        case 5: g1_body<5>(pl, pg, ap, ldsb, wave, lane, accl, accg); break;
        case 6: g1_body<6>(pl, pg, ap, ldsb, wave, lane, accl, accg); break;
        case 7: g1_body<7>(pl, pg, ap, ldsb, wave, lane, accl, accg); break;
        default: g1_body<8>(pl, pg, ap, ldsb, wave, lane, accl, accg); break;
    }

    int n0 = n0b + wave * 16;
#pragma unroll
    for (int m = 0; m < 8; ++m) {
        if (m * 16 < c) {
#pragma unroll
            for (int r = 0; r < 4; ++r) {
                int slot = m * 16 + lq * 4 + r;
                if (slot < c) {
                    float lin  = accl[m][r];
                    float gate = accg[m][r];
                    float a = lin * (1.0f / (1.0f + __expf(-lin))) * gate;
                    act[((size_t)e * T_TOK + slot) * INTER + n0 + lr] = (__bf16)a;
                }
            }
        }
    }
}

// ---------------------------------------------------------------------------
// Kernel 4: GEMM2 + scaled scatter-add. K-split 4, staged through LDS.
// ---------------------------------------------------------------------------
#define KSPLIT 4
#define KCH (INTER / KSPLIT)   // 1024

template<int MG>
__device__ __forceinline__ void g2_body(const float* __restrict__ pw,
                                        const __bf16* __restrict__ ap,
                                        char* __restrict__ ldsb,
                                        int wave, int lane,
                                        f32x4* __restrict__ acc) {
    const int lr = lane & 15, lq = lane >> 4;
    const int sread = (lr & 7) << 4;
    const char* bp = ldsb + (size_t)(wave * 16 + lr) * LDS_ROWB;

    for (int ks = 0; ks < KCH; ks += BK1) {
        // ---- stage: 64 rows x 256 f32 -> bf16 LDS ----
#pragma unroll 8
        for (int it = 0; it < 16; ++it) {
            int row = it * 4 + wave;          // 0..63
            float4 v = *(const float4*)(pw + (size_t)row * INTER + ks);
            bf16x4 pk;
            pk[0] = (__bf16)v.x; pk[1] = (__bf16)v.y;
            pk[2] = (__bf16)v.z; pk[3] = (__bf16)v.w;
            *(bf16x4*)(ldsb + (size_t)row * LDS_ROWB +
                       ((lane * 8) ^ ((row & 7) << 4))) = pk;
        }
        __syncthreads();
#pragma unroll
        for (int kk = 0; kk < BK1; kk += 32) {
            int off = (kk * 2 + lq * 16) ^ sread;
            bf16x8 B = *(const bf16x8*)(bp + off);
            bf16x8 A[MG];
#pragma unroll
            for (int m = 0; m < MG; ++m)
                A[m] = *(const bf16x8*)(ap + (size_t)m * 16 * INTER + ks + kk);
#pragma unroll
            for (int m = 0; m < MG; ++m)
                acc[m] = __builtin_amdgcn_mfma_f32_16x16x32_bf16(A[m], B, acc[m], 0, 0, 0);
        }
        __syncthreads();
    }
}

__global__ __launch_bounds__(256) void gemm2_kernel(
    const float* __restrict__ w2,
    const int* __restrict__ cnt,
    const int* __restrict__ tok,
    const float* __restrict__ scal,
    const __bf16* __restrict__ act,
    float* __restrict__ out) {
    __shared__ __align__(16) __bf16 lds[64 * BK1];    // 32 KB
    int bx = blockIdx.x;                 // 0..511 : e(3) | nb(4) | ks(2)
    int ksc = bx & (KSPLIT - 1), nb = (bx >> 2) & 15, e = bx >> 6;
    int wave = threadIdx.x >> 6, lane = threadIdx.x & 63;
    int c  = cnt[e];
    if (c == 0) return;
    int mgs = (c + 15) >> 4;
    int lr = lane & 15, lq = lane >> 4;
    int n0b = nb * 64;

    const float* pw  = w2 + ((size_t)e * HID + n0b) * INTER + ksc * KCH + lane * 4;
    const __bf16* ap = act + ((size_t)e * T_TOK + lr) * INTER + ksc * KCH + lq * 8;

    f32x4 acc[8];
#pragma unroll
    for (int m = 0; m < 8; ++m) acc[m] = (f32x4){0.f, 0.f, 0.f, 0.f};

    char* ldsb = (char*)lds;
    switch (mgs) {
        case 1: g2_body<1>(pw, ap, ldsb, wave, lane, acc); break;
        case 2: g2_body<2>(pw, ap, ldsb, wave, lane, acc); break;
        case 3: g2_body<3>(pw, ap, ldsb, wave, lane, acc); break;
        case 4: g2_body<4>(pw, ap, ldsb, wave, lane, acc); break;
        case 5: g2_body<5>(pw, ap, ldsb, wave, lane, acc); break;
        case 6: g2_body<6>(pw, ap, ldsb, wave, lane, acc); break;
        case 7: g2_body<7>(pw, ap, ldsb, wave, lane, acc); break;
        default: g2_body<8>(pw, ap, ldsb, wave, lane, acc); break;
    }

    int n0 = n0b + wave * 16;
#pragma unroll
    for (int m = 0; m < 8; ++m) {
        if (m * 16 < c) {
#pragma unroll
            for (int r = 0; r < 4; ++r) {
                int slot = m * 16 + lq * 4 + r;
                if (slot < c) {
                    int   t    = tok [e * T_TOK + slot];
                    float coef = scal[e * T_TOK + slot];
                    atomicAdd(&out[(size_t)t * HID + n0 + lr], coef * acc[m][r]);
                }
            }
        }
    }
}

// ---------------------------------------------------------------------------
// Workspace layout (bytes):
//   [0,32)            cnt[8]
//   [64, 64+4096)     tok_list[8][128]
//   [4160, 8256)      tok_scale[8][128]
//   [16384, +2MB)     abuf  bf16 [8][128][1024]
//   [16384+2MB, +8MB) act   bf16 [8][128][4096]
// ---------------------------------------------------------------------------
extern "C" void kernel_launch(void* const* d_in, const int* in_sizes, int n_in,
                              void* d_out, int out_size, void* d_ws, size_t ws_size,
                              hipStream_t stream) {
    const float* hidden  = (const float*)d_in[0];
    const float* routing = (const float*)d_in[1];
    const float* w1      = (const float*)d_in[2];
    const float* w2      = (const float*)d_in[3];
    float* out = (float*)d_out;

    char* ws = (char*)d_ws;
    int*    cnt  = (int*)ws;
    int*    tok  = (int*)(ws + 64);
    float*  scal = (float*)(ws + 64 + 4096);
    __bf16* abuf = (__bf16*)(ws + 16384);
    __bf16* act  = (__bf16*)(ws + 16384 + (size_t)2 * 1024 * 1024);

    hipMemsetAsync(d_out, 0, (size_t)out_size * sizeof(float), stream);

    route_kernel<<<1, 128, 0, stream>>>(routing, cnt, tok, scal);
    prep_kernel<<<N_EXP * T_TOK, 64, 0, stream>>>(hidden, cnt, tok, abuf);
    gemm1_kernel<<<N_EXP * 64, 256, 0, stream>>>(w1, cnt, abuf, act);
    gemm2_kernel<<<N_EXP * 16 * KSPLIT, 256, 0, stream>>>(w2, cnt, tok, scal, act, out);
}

// Round 2
// 483.149 us; speedup vs baseline: 1.0030x; 1.0011x over previous
//
#include <hip/hip_runtime.h>
#include <hip/hip_bf16.h>

// Problem constants
#define T_TOK 128
#define N_EXP 8
#define HID   1024
#define INTER 4096

typedef __bf16 bf16x8 __attribute__((ext_vector_type(8)));
typedef __bf16 bf16x4 __attribute__((ext_vector_type(4)));
typedef float  f32x4  __attribute__((ext_vector_type(4)));

// Async global -> LDS, 16 B per lane (wave-uniform LDS base + lane*16).
#define GLOAD_LDS16(gp, lp)                                                   \
    __builtin_amdgcn_global_load_lds(                                         \
        (const __attribute__((address_space(1))) void*)(gp),                  \
        (__attribute__((address_space(3))) void*)(lp), 16, 0, 0)

// ---------------------------------------------------------------------------
// Kernel 1: routing. softmax over 8 logits -> top2 -> renormalized scales.
// ---------------------------------------------------------------------------
__global__ void route_kernel(const float* __restrict__ routing,
                             int* __restrict__ cnt,
                             int* __restrict__ tok,
                             float* __restrict__ scal) {
    int t = threadIdx.x;            // token id 0..127
    int wave = t >> 6, lane = t & 63;

    float l[N_EXP];
#pragma unroll
    for (int e = 0; e < N_EXP; ++e) l[e] = routing[t * N_EXP + e];

    int i1 = 0; float v1 = l[0];
#pragma unroll
    for (int e = 1; e < N_EXP; ++e) if (l[e] > v1) { v1 = l[e]; i1 = e; }
    int i2 = -1; float v2 = -1e30f;
#pragma unroll
    for (int e = 0; e < N_EXP; ++e) if (e != i1 && l[e] > v2) { v2 = l[e]; i2 = e; }

    float s1 = 1.0f / (1.0f + __expf(v2 - v1));
    float s2 = 1.0f - s1;

    __shared__ unsigned long long wmask[2][N_EXP];
#pragma unroll
    for (int e = 0; e < N_EXP; ++e) {
        bool sel = (i1 == e) || (i2 == e);
        unsigned long long m = __ballot(sel);
        if (lane == 0) wmask[wave][e] = m;
    }
    __syncthreads();
#pragma unroll
    for (int e = 0; e < N_EXP; ++e) {
        bool sel = (i1 == e) || (i2 == e);
        unsigned long long m = __ballot(sel);
        int pre  = __popcll(m & ((1ull << lane) - 1ull));
        int base = (wave == 1) ? __popcll(wmask[0][e]) : 0;
        if (sel) {
            int slot = base + pre;
            tok [e * T_TOK + slot] = t;
            scal[e * T_TOK + slot] = (i1 == e) ? s1 : s2;
        }
        if (t == 0) cnt[e] = __popcll(wmask[0][e]) + __popcll(wmask[1][e]);
    }
}

// ---------------------------------------------------------------------------
// Kernel 2: gather routed hidden rows into compact bf16 A-buffer.
// ---------------------------------------------------------------------------
__global__ void prep_kernel(const float* __restrict__ hidden,
                            const int* __restrict__ cnt,
                            const int* __restrict__ tok,
                            __bf16* __restrict__ abuf) {
    int b = blockIdx.x;
    int e = b >> 7, s = b & 127;
    if (s >= cnt[e]) return;
    int t = tok[e * T_TOK + s];
    const float4* src = (const float4*)(hidden + (size_t)t * HID);
    __bf16* dst = abuf + ((size_t)e * T_TOK + s) * HID;
#pragma unroll
    for (int it = 0; it < 4; ++it) {
        int idx = it * 64 + threadIdx.x;
        float4 v = src[idx];
        bf16x4 pk;
        pk[0] = (__bf16)v.x; pk[1] = (__bf16)v.y;
        pk[2] = (__bf16)v.z; pk[3] = (__bf16)v.w;
        *(bf16x4*)(dst + idx * 4) = pk;
    }
}

__device__ __forceinline__ bf16x8 cvt8(float4 a, float4 b) {
    bf16x8 r;
    r[0] = (__bf16)a.x; r[1] = (__bf16)a.y; r[2] = (__bf16)a.z; r[3] = (__bf16)a.w;
    r[4] = (__bf16)b.x; r[5] = (__bf16)b.y; r[6] = (__bf16)b.z; r[7] = (__bf16)b.w;
    return r;
}

// ---------------------------------------------------------------------------
// Async 2-phase pipelined GEMMs.
//
// Weights staged fp32 directly to LDS via global_load_lds (no VGPR roundtrip).
// LDS layout: [rows][64 f32] rows of 256 B = 16 chunks of 16 B. Chunk swizzle:
// logical chunk L of row R lives at physical chunk L ^ (R&7). global_load_lds
// writes linearly, so the swizzle is applied on the per-lane GLOBAL source
// address (rule: both-sides-or-neither); ds_read applies the same XOR.
// Per K-step (64 f32): issue next-tile loads BEFORE computing current tile;
// single vmcnt-drain+barrier per step keeps HBM busy under the compute.
// ---------------------------------------------------------------------------

// stage 8 x (4 rows x 256B) per wave, row stride HID*4 in global
__device__ __forceinline__ void g1_stage(const char* pe, const char* po,
                                         char* dstbase, int ksb) {
#pragma unroll
    for (int i = 0; i < 8; ++i) {
        const char* src = ((i & 1) ? po : pe) + (size_t)(i * 4) * (HID * 4) + ksb;
        GLOAD_LDS16(src, dstbase + i * 1024);
    }
}

template<int MG>
__device__ __forceinline__ void g1_compute(const char* __restrict__ buf,
                                           const __bf16* __restrict__ ap,
                                           int ksf, int wave, int lr,
                                           const int* __restrict__ coff,
                                           f32x4* __restrict__ accl,
                                           f32x4* __restrict__ accg) {
    const char* rowL = buf + (size_t)(wave * 16 + lr) * 256;
    const char* rowG = rowL + 64 * 256;
#pragma unroll
    for (int kk = 0; kk < 2; ++kk) {
        float4 l0 = *(const float4*)(rowL + coff[kk * 2]);
        float4 l1 = *(const float4*)(rowL + coff[kk * 2 + 1]);
        float4 g0 = *(const float4*)(rowG + coff[kk * 2]);
        float4 g1 = *(const float4*)(rowG + coff[kk * 2 + 1]);
        bf16x8 BL = cvt8(l0, l1);
        bf16x8 BG = cvt8(g0, g1);
        bf16x8 A[MG];
#pragma unroll
        for (int m = 0; m < MG; ++m)
            A[m] = *(const bf16x8*)(ap + (size_t)m * 16 * HID + ksf + kk * 32);
#pragma unroll
        for (int m = 0; m < MG; ++m) {
            accl[m] = __builtin_amdgcn_mfma_f32_16x16x32_bf16(A[m], BL, accl[m], 0, 0, 0);
            accg[m] = __builtin_amdgcn_mfma_f32_16x16x32_bf16(A[m], BG, accg[m], 0, 0, 0);
        }
    }
}

template<int MG>
__device__ __forceinline__ void g1_pipe(const char* pe, const char* po,
                                        char* ldsbase, int ldrow_off,
                                        const __bf16* ap, const int* coff,
                                        int wave, int lr,
                                        f32x4* accl, f32x4* accg) {
    g1_stage(pe, po, ldsbase + ldrow_off, 0);
    __syncthreads();
#pragma unroll 2
    for (int s = 0; s < 16; ++s) {
        int b = s & 1;
        if (s + 1 < 16)
            g1_stage(pe, po, ldsbase + (b ^ 1) * 32768 + ldrow_off, (s + 1) * 256);
        g1_compute<MG>(ldsbase + b * 32768, ap, s * 64, wave, lr, coff, accl, accg);
        __syncthreads();
    }
}

__global__ __launch_bounds__(256) void gemm1_kernel(
    const float* __restrict__ w1,
    const int* __restrict__ cnt,
    const __bf16* __restrict__ abuf,
    __bf16* __restrict__ act) {
    __shared__ __align__(16) char lds[2 * 32768];   // 64 KB dbuf: 128 rows x 256 B
    int bx = blockIdx.x;                 // 0..511
    int e  = bx >> 6, nb = bx & 63;
    int wave = threadIdx.x >> 6, lane = threadIdx.x & 63;
    int c  = cnt[e];
    if (c == 0) return;
    int mgs = (c + 15) >> 4;
    int lr = lane & 15;
    int lq = lane >> 4;
    int n0b = nb * 64;

    // ---- stage-side per-lane source addresses ----
    int lhi = lane >> 4;        // row-within-instr 0..3
    int lch = lane & 15;        // chunk position 0..15
    int half = wave & 1, gate = wave >> 1;   // waves 0,1 -> lin rows; 2,3 -> gate
    const char* w1b  = (const char*)w1 + (size_t)e * 2 * INTER * HID * 4;
    const char* srcb = w1b + ((size_t)gate * INTER + n0b + half * 32 + lhi) * (size_t)(HID * 4);
    const char* pe = srcb + ((lch ^ lhi) << 4);          // even i: row&7 = lhi
    const char* po = srcb + ((lch ^ (4 + lhi)) << 4);    // odd  i: row&7 = 4+lhi
    int ldrow_off = (half * 32 + gate * 64) * 256;

    // ---- read-side swizzled chunk offsets (constant across K-steps) ----
    int coff[4];
#pragma unroll
    for (int kk = 0; kk < 2; ++kk)
#pragma unroll
        for (int j = 0; j < 2; ++j)
            coff[kk * 2 + j] = ((kk * 8 + lq * 2 + j) ^ (lr & 7)) << 4;

    const __bf16* ap = abuf + ((size_t)e * T_TOK + lr) * HID + lq * 8;

    f32x4 accl[8], accg[8];
#pragma unroll
    for (int m = 0; m < 8; ++m) {
        accl[m] = (f32x4){0.f, 0.f, 0.f, 0.f};
        accg[m] = (f32x4){0.f, 0.f, 0.f, 0.f};
    }

    switch (mgs) {
        case 1: g1_pipe<1>(pe, po, lds, ldrow_off, ap, coff, wave, lr, accl, accg); break;
        case 2: g1_pipe<2>(pe, po, lds, ldrow_off, ap, coff, wave, lr, accl, accg); break;
        case 3: g1_pipe<3>(pe, po, lds, ldrow_off, ap, coff, wave, lr, accl, accg); break;
        case 4: g1_pipe<4>(pe, po, lds, ldrow_off, ap, coff, wave, lr, accl, accg); break;
        case 5: g1_pipe<5>(pe, po, lds, ldrow_off, ap, coff, wave, lr, accl, accg); break;
        case 6: g1_pipe<6>(pe, po, lds, ldrow_off, ap, coff, wave, lr, accl, accg); break;
        case 7: g1_pipe<7>(pe, po, lds, ldrow_off, ap, coff, wave, lr, accl, accg); break;
        default: g1_pipe<8>(pe, po, lds, ldrow_off, ap, coff, wave, lr, accl, accg); break;
    }

    int n0 = n0b + wave * 16;
#pragma unroll
    for (int m = 0; m < 8; ++m) {
        if (m * 16 < c) {
#pragma unroll
            for (int r = 0; r < 4; ++r) {
                int slot = m * 16 + lq * 4 + r;
                if (slot < c) {
                    float lin  = accl[m][r];
                    float gate_v = accg[m][r];
                    float a = lin * (1.0f / (1.0f + __expf(-lin))) * gate_v;
                    act[((size_t)e * T_TOK + slot) * INTER + n0 + lr] = (__bf16)a;
                }
            }
        }
    }
}

// ---------------------------------------------------------------------------
// Kernel 4: GEMM2 + scaled scatter-add. K-split 4, async 2-phase pipeline.
// ---------------------------------------------------------------------------
#define KSPLIT 4
#define KCH (INTER / KSPLIT)   // 1024

__device__ __forceinline__ void g2_stage(const char* pe, const char* po,
                                         char* dstbase, int ksb) {
#pragma unroll
    for (int i = 0; i < 4; ++i) {
        const char* src = ((i & 1) ? po : pe) + (size_t)(i * 4) * (INTER * 4) + ksb;
        GLOAD_LDS16(src, dstbase + i * 1024);
    }
}

template<int MG>
__device__ __forceinline__ void g2_compute(const char* __restrict__ buf,
                                           const __bf16* __restrict__ ap,
                                           int ksf, int wave, int lr,
                                           const int* __restrict__ coff,
                                           f32x4* __restrict__ acc) {
    const char* row = buf + (size_t)(wave * 16 + lr) * 256;
#pragma unroll
    for (int kk = 0; kk < 2; ++kk) {
        float4 q0 = *(const float4*)(row + coff[kk * 2]);
        float4 q1 = *(const float4*)(row + coff[kk * 2 + 1]);
        bf16x8 B = cvt8(q0, q1);
        bf16x8 A[MG];
#pragma unroll
        for (int m = 0; m < MG; ++m)
            A[m] = *(const bf16x8*)(ap + (size_t)m * 16 * INTER + ksf + kk * 32);
#pragma unroll
        for (int m = 0; m < MG; ++m)
            acc[m] = __builtin_amdgcn_mfma_f32_16x16x32_bf16(A[m], B, acc[m], 0, 0, 0);
    }
}

template<int MG>
__device__ __forceinline__ void g2_pipe(const char* pe, const char* po,
                                        char* ldsbase, int ldrow_off,
                                        const __bf16* ap, const int* coff,
                                        int wave, int lr,
                                        f32x4* acc) {
    g2_stage(pe, po, ldsbase + ldrow_off, 0);
    __syncthreads();
#pragma unroll 2
    for (int s = 0; s < 16; ++s) {
        int b = s & 1;
        if (s + 1 < 16)
            g2_stage(pe, po, ldsbase + (b ^ 1) * 16384 + ldrow_off, (s + 1) * 256);
        g2_compute<MG>(ldsbase + b * 16384, ap, s * 64, wave, lr, coff, acc);
        __syncthreads();
    }
}

__global__ __launch_bounds__(256) void gemm2_kernel(
    const float* __restrict__ w2,
    const int* __restrict__ cnt,
    const int* __restrict__ tok,
    const float* __restrict__ scal,
    const __bf16* __restrict__ act,
    float* __restrict__ out) {
    __shared__ __align__(16) char lds[2 * 16384];   // 32 KB dbuf: 64 rows x 256 B
    int bx = blockIdx.x;                 // 0..511 : e(3) | nb(4) | ks(2)
    int ksc = bx & (KSPLIT - 1), nb = (bx >> 2) & 15, e = bx >> 6;
    int wave = threadIdx.x >> 6, lane = threadIdx.x & 63;
    int c  = cnt[e];
    if (c == 0) return;
    int mgs = (c + 15) >> 4;
    int lr = lane & 15, lq = lane >> 4;
    int n0b = nb * 64;

    // ---- stage-side per-lane source addresses (wave w stages rows w*16..+15) ----
    int lhi = lane >> 4;
    int lch = lane & 15;
    const char* srcb = (const char*)w2 +
        ((size_t)e * HID + n0b + wave * 16 + lhi) * (size_t)(INTER * 4) +
        (size_t)ksc * (KCH * 4);
    const char* pe = srcb + ((lch ^ lhi) << 4);
    const char* po = srcb + ((lch ^ (4 + lhi)) << 4);
    int ldrow_off = wave * 4096;

    int coff[4];
#pragma unroll
    for (int kk = 0; kk < 2; ++kk)
#pragma unroll
        for (int j = 0; j < 2; ++j)
            coff[kk * 2 + j] = ((kk * 8 + lq * 2 + j) ^ (lr & 7)) << 4;

    const __bf16* ap = act + ((size_t)e * T_TOK + lr) * INTER + ksc * KCH + lq * 8;

    f32x4 acc[8];
#pragma unroll
    for (int m = 0; m < 8; ++m) acc[m] = (f32x4){0.f, 0.f, 0.f, 0.f};

    switch (mgs) {
        case 1: g2_pipe<1>(pe, po, lds, ldrow_off, ap, coff, wave, lr, acc); break;
        case 2: g2_pipe<2>(pe, po, lds, ldrow_off, ap, coff, wave, lr, acc); break;
        case 3: g2_pipe<3>(pe, po, lds, ldrow_off, ap, coff, wave, lr, acc); break;
        case 4: g2_pipe<4>(pe, po, lds, ldrow_off, ap, coff, wave, lr, acc); break;
        case 5: g2_pipe<5>(pe, po, lds, ldrow_off, ap, coff, wave, lr, acc); break;
        case 6: g2_pipe<6>(pe, po, lds, ldrow_off, ap, coff, wave, lr, acc); break;
        case 7: g2_pipe<7>(pe, po, lds, ldrow_off, ap, coff, wave, lr, acc); break;
        default: g2_pipe<8>(pe, po, lds, ldrow_off, ap, coff, wave, lr, acc); break;
    }

    int n0 = n0b + wave * 16;
#pragma unroll
    for (int m = 0; m < 8; ++m) {
        if (m * 16 < c) {
#pragma unroll
            for (int r = 0; r < 4; ++r) {
                int slot = m * 16 + lq * 4 + r;
                if (slot < c) {
                    int   t    = tok [e * T_TOK + slot];
                    float coef = scal[e * T_TOK + slot];
                    atomicAdd(&out[(size_t)t * HID + n0 + lr], coef * acc[m][r]);
                }
            }
        }
    }
}

// ---------------------------------------------------------------------------
// Workspace layout (bytes):
//   [0,32)            cnt[8]
//   [64, 64+4096)     tok_list[8][128]
//   [4160, 8256)      tok_scale[8][128]
//   [16384, +2MB)     abuf  bf16 [8][128][1024]
//   [16384+2MB, +8MB) act   bf16 [8][128][4096]
// ---------------------------------------------------------------------------
extern "C" void kernel_launch(void* const* d_in, const int* in_sizes, int n_in,
                              void* d_out, int out_size, void* d_ws, size_t ws_size,
                              hipStream_t stream) {
    const float* hidden  = (const float*)d_in[0];
    const float* routing = (const float*)d_in[1];
    const float* w1      = (const float*)d_in[2];
    const float* w2      = (const float*)d_in[3];
    float* out = (float*)d_out;

    char* ws = (char*)d_ws;
    int*    cnt  = (int*)ws;
    int*    tok  = (int*)(ws + 64);
    float*  scal = (float*)(ws + 64 + 4096);
    __bf16* abuf = (__bf16*)(ws + 16384);
    __bf16* act  = (__bf16*)(ws + 16384 + (size_t)2 * 1024 * 1024);

    hipMemsetAsync(d_out, 0, (size_t)out_size * sizeof(float), stream);

    route_kernel<<<1, 128, 0, stream>>>(routing, cnt, tok, scal);
    prep_kernel<<<N_EXP * T_TOK, 64, 0, stream>>>(hidden, cnt, tok, abuf);
    gemm1_kernel<<<N_EXP * 64, 256, 0, stream>>>(w1, cnt, abuf, act);
    gemm2_kernel<<<N_EXP * 16 * KSPLIT, 256, 0, stream>>>(w2, cnt, tok, scal, act, out);
}